// Round 9
// baseline (520.427 us; speedup 1.0000x reference)
//
#include <hip/hip_runtime.h>
#include <hip/hip_bf16.h>

// TreeLSTM, 128 perfect binary trees, depth 9, H=256. N=130944 nodes.
//
// R8: B-operand (weights, L2-resident) moved LDS -> REGISTERS, loaded direct
// from global 2-deep. A stays global_load_lds double-buffered. Raw s_barrier
// + in-order counted vmcnt: issue order [A(i),B(i),A(i+1),B(i+1)] repeating,
// so vmcnt(7) (level: 2+5) / vmcnt(5) (leaf: 2+3) at iter top drains exactly
// A(i)+B(i); vmcnt(0) on final iter. LDS = a_s only (16KB/block).
//
// ws (bf16): Wt[768*256], Ut[1280*512], s_full[N*256], x_bf[65536*256],
//            hA,cmA [T*512 rows], hB,cmB [T*256 rows]  (T=128: 253 MiB)

#define NTREES 128
#define NPT    1023
#define HS     256
#define NNODES (NTREES * NPT)
#define NL     (NTREES * 512)

typedef __hip_bfloat16 bf16;
typedef unsigned short us8 __attribute__((ext_vector_type(8)));
typedef unsigned short us4 __attribute__((ext_vector_type(4)));
typedef short bf16x8 __attribute__((ext_vector_type(8)));
typedef float f32x4 __attribute__((ext_vector_type(4)));

typedef __attribute__((address_space(1))) const void gvoid;
typedef __attribute__((address_space(3))) void svoid;
#define GLD16(gp, lp) \
    __builtin_amdgcn_global_load_lds((gvoid*)(gp), (svoid*)(lp), 16, 0, 0)
#define SBAR()  __builtin_amdgcn_s_barrier()
#define SCHED() __builtin_amdgcn_sched_barrier(0)

__device__ __forceinline__ float bits2f(unsigned short b) {
    return __uint_as_float(((unsigned)b) << 16);
}
__device__ __forceinline__ unsigned short f2bits(float x) {
    bf16 h = __float2bfloat16(x);
    return *reinterpret_cast<unsigned short*>(&h);
}
__device__ __forceinline__ float fsigm(float x) {
    return __builtin_amdgcn_rcpf(1.0f + __expf(-x));
}
__device__ __forceinline__ float ftanh(float x) {
    return 1.0f - 2.0f * __builtin_amdgcn_rcpf(1.0f + __expf(2.0f * x));
}

// ---------------------------------------------------------------------------
#define WT_ELEMS (768 * 256)
#define UT_ELEMS (1280 * 512)

__global__ __launch_bounds__(256) void prep_w(
    const float* __restrict__ W_iou, const float* __restrict__ U_f_w,
    const float* __restrict__ U_iou, bf16* __restrict__ Wt, bf16* __restrict__ Ut)
{
    const int i = blockIdx.x * 256 + threadIdx.x;
    if (i < WT_ELEMS) {
        const int n = i >> 8, k = i & 255;
        Wt[i] = __float2bfloat16(W_iou[k * 768 + n]);
    } else if (i < WT_ELEMS + UT_ELEMS) {
        const int j = i - WT_ELEMS;
        const int n = j >> 9, k = j & 511;
        const float v = (n < 512) ? U_f_w[k * 512 + n] : U_iou[k * 768 + (n - 512)];
        Ut[j] = __float2bfloat16(v);
    }
}

// ---------------------------------------------------------------------------
// gather_x: x_bf[gr][0:256] = mask ? bf16(emb[wordid]) : 0.  Wave per row.
// ---------------------------------------------------------------------------
__global__ __launch_bounds__(256) void gather_x(
    const int* __restrict__ wordid, const int* __restrict__ mask,
    const float* __restrict__ emb, bf16* __restrict__ x_bf)
{
    const int wave = threadIdx.x >> 6, lane = threadIdx.x & 63;
    const int gr   = blockIdx.x * 4 + wave;
    const int node = (gr >> 9) * NPT + 511 + (gr & 511);
    const int j0   = lane * 4;
    us4 v;
    if (mask[node]) {
        const float4 f = *(const float4*)(emb + (long)wordid[node] * HS + j0);
        v[0] = f2bits(f.x); v[1] = f2bits(f.y);
        v[2] = f2bits(f.z); v[3] = f2bits(f.w);
    } else {
        v[0] = v[1] = v[2] = v[3] = 0;
    }
    *(us4*)(x_bf + (long)gr * HS + j0) = v;
}

// ---------------------------------------------------------------------------
// Fused leaf. Tile 128 rows x (32j x 3 gates). A: LDS dbuf; B: regs 2-deep.
// Per iter groups: A=2 GLD16, B=3 reg-loads -> vmcnt(5) steady, (0) last.
// ---------------------------------------------------------------------------
__global__ __launch_bounds__(256) void leaf_fused(
    const bf16* __restrict__ x_bf, const bf16* __restrict__ Wt,
    const float* __restrict__ b_iou,
    bf16* __restrict__ h_s, bf16* __restrict__ cm_s,
    bf16* __restrict__ s_full, const int tree0)
{
    __shared__ __align__(16) short a_s[2][128 * 32];
    const int t    = threadIdx.x;
    const int bm0  = blockIdx.x * 128;
    const int c0   = blockIdx.y * 32;
    const int lane = t & 63, wave = t >> 6;
    const int l4a = lane >> 2, k8 = (lane & 3) * 8;

    const int wr = wave >> 1, wc = wave & 1;
    const int fr = lane & 15, l4 = lane >> 4;

    // A: 8 GLD16 (2/wave) from x_bf rows
    const bf16* aSrc[2];
    #pragma unroll
    for (int q = 0; q < 2; ++q) {
        const int row = (wave * 2 + q) * 16 + l4a;
        aSrc[q] = x_bf + (long)(tree0 * 512 + bm0 + row) * HS + k8;
    }
    // B: direct-to-reg. lane reads Wt row n = g*256 + c0 + wc*16 + fr,
    // elems kt + l4*8 (16 rows x 64B contiguous per instr = 16 cachelines).
    const bf16* bPtr[3];
    #pragma unroll
    for (int g = 0; g < 3; ++g)
        bPtr[g] = Wt + (long)(g * 256 + c0 + wc * 16 + fr) * 256 + l4 * 8;

    f32x4 acc[4][3];
    #pragma unroll
    for (int i = 0; i < 4; ++i)
        #pragma unroll
        for (int g = 0; g < 3; ++g) acc[i][g] = (f32x4){0.f, 0.f, 0.f, 0.f};

    bf16x8 bgE[3], bgO[3];   // even/odd iteration B registers

    // Prologue order: A(0), B(0)->bgE, A(1), B(1)->bgO
    #pragma unroll
    for (int q = 0; q < 2; ++q) GLD16(aSrc[q], &a_s[0][(wave * 2 + q) * 512]);
    SCHED();
    #pragma unroll
    for (int g = 0; g < 3; ++g) bgE[g] = *(const bf16x8*)(bPtr[g]);
    SCHED();
    #pragma unroll
    for (int q = 0; q < 2; ++q) GLD16(aSrc[q] + 32, &a_s[1][(wave * 2 + q) * 512]);
    SCHED();
    #pragma unroll
    for (int g = 0; g < 3; ++g) bgO[g] = *(const bf16x8*)(bPtr[g] + 32);
    SCHED();

    #pragma unroll
    for (int it = 0; it < 8; ++it) {
        const int cur = it & 1;
        if (it < 7) { asm volatile("s_waitcnt vmcnt(5)" ::: "memory"); }
        else        { asm volatile("s_waitcnt vmcnt(0)" ::: "memory"); }
        SCHED(); SBAR(); SCHED();
        bf16x8 af[4];
        #pragma unroll
        for (int i = 0; i < 4; ++i)
            af[i] = *(const bf16x8*)&a_s[cur][(wr * 64 + i * 16 + fr) * 32 + l4 * 8];
        #pragma unroll
        for (int i = 0; i < 4; ++i)
            #pragma unroll
            for (int g = 0; g < 3; ++g)
                acc[i][g] = __builtin_amdgcn_mfma_f32_16x16x32_bf16(
                    cur ? bgO[g] : bgE[g], af[i], acc[i][g], 0, 0, 0);
        SCHED();
        if (it + 2 < 8) {   // issue B(it+2) into same-parity regs
            #pragma unroll
            for (int g = 0; g < 3; ++g) {
                if (cur) bgO[g] = *(const bf16x8*)(bPtr[g] + (it + 2) * 32);
                else     bgE[g] = *(const bf16x8*)(bPtr[g] + (it + 2) * 32);
            }
        }
        SCHED(); SBAR(); SCHED();
        if (it + 2 < 8) {   // issue A(it+2) into a_s[cur]
            #pragma unroll
            for (int q = 0; q < 2; ++q)
                GLD16(aSrc[q] + (it + 2) * 32, &a_s[cur][(wave * 2 + q) * 512]);
        }
        SCHED();
    }

    // Epilogue: lane owns row r (fr), 4 consecutive j (reg q).
    const int j0 = c0 + wc * 16 + l4 * 4;
    const float4 bi4 = *(const float4*)(b_iou + j0);
    const float4 bo4 = *(const float4*)(b_iou + 256 + j0);
    const float4 bu4 = *(const float4*)(b_iou + 512 + j0);
    #pragma unroll
    for (int i = 0; i < 4; ++i) {
        const int r    = bm0 + wr * 64 + i * 16 + fr;
        const int gr   = tree0 * 512 + r;
        const int node = (gr >> 9) * NPT + 511 + (gr & 511);
        us4 sh, ss; us8 scm;
        #pragma unroll
        for (int q = 0; q < 4; ++q) {
            const float iv = fsigm(acc[i][0][q] + ((const float*)&bi4)[q]);
            const float ov = fsigm(acc[i][1][q] + ((const float*)&bo4)[q]);
            const float uv = ftanh(acc[i][2][q] + ((const float*)&bu4)[q]);
            const float cv  = iv * uv;
            const float hv  = ov * ftanh(cv);
            const float mhv = fmaxf(hv, 0.0f);
            sh[q] = f2bits(hv); ss[q] = f2bits(hv + mhv);
            scm[2 * q] = f2bits(cv); scm[2 * q + 1] = f2bits(mhv);
        }
        *(us4*)(h_s + (long)r * HS + j0)        = sh;
        *(us8*)(cm_s + (long)r * 512 + j0 * 2)  = scm;
        *(us4*)(s_full + (long)node * HS + j0)  = ss;
    }
}

// ---------------------------------------------------------------------------
// Fused level. Tile 128 rows x (32j x 5 gates). A: LDS dbuf; B: regs 2-deep.
// Per iter groups: A=2 GLD16, B=5 reg-loads -> vmcnt(7) steady, (0) last.
// ---------------------------------------------------------------------------
__global__ __launch_bounds__(256) void level_fused(
    const bf16* __restrict__ h_child, const bf16* __restrict__ cm_c,
    const bf16* __restrict__ Ut,
    const float* __restrict__ U_f_b, const float* __restrict__ b_iou,
    bf16* __restrict__ h_p, bf16* __restrict__ cm_p,
    bf16* __restrict__ s_full, const int lvl, const int M, const int tree0)
{
    __shared__ __align__(16) short a_s[2][128 * 32];
    const int t    = threadIdx.x;
    const int bm0  = blockIdx.x * 128;
    const int c0   = blockIdx.y * 32;
    const int lane = t & 63, wave = t >> 6;
    const int l4a = lane >> 2, k8 = (lane & 3) * 8;

    const int wr = wave >> 1, wc = wave & 1;
    const int fr = lane & 15, l4 = lane >> 4;

    // A: 8 GLD16 (2/wave). Row -> parent p -> adjacent child-pair rows.
    const bf16* aSrc[2];
    #pragma unroll
    for (int q = 0; q < 2; ++q) {
        int p = bm0 + (wave * 2 + q) * 16 + l4a;
        if (p >= M) p = M - 1;
        const int tl  = p >> lvl;
        const int idx = p & ((1 << lvl) - 1);
        const int cls = tl * (2 << lvl) + 2 * idx;
        aSrc[q] = h_child + (long)cls * HS + k8;  // 512 contiguous (2 children)
    }
    // B: direct-to-reg from Ut; row n = g*256 + c0 + wc*16 + fr.
    const bf16* bPtr[5];
    #pragma unroll
    for (int g = 0; g < 5; ++g)
        bPtr[g] = Ut + (long)(g * 256 + c0 + wc * 16 + fr) * 512 + l4 * 8;

    f32x4 acc[4][5];
    #pragma unroll
    for (int i = 0; i < 4; ++i)
        #pragma unroll
        for (int g = 0; g < 5; ++g) acc[i][g] = (f32x4){0.f, 0.f, 0.f, 0.f};

    bf16x8 bgE[5], bgO[5];

    // Prologue order: A(0), B(0)->bgE, A(1), B(1)->bgO
    #pragma unroll
    for (int q = 0; q < 2; ++q) GLD16(aSrc[q], &a_s[0][(wave * 2 + q) * 512]);
    SCHED();
    #pragma unroll
    for (int g = 0; g < 5; ++g) bgE[g] = *(const bf16x8*)(bPtr[g]);
    SCHED();
    #pragma unroll
    for (int q = 0; q < 2; ++q) GLD16(aSrc[q] + 32, &a_s[1][(wave * 2 + q) * 512]);
    SCHED();
    #pragma unroll
    for (int g = 0; g < 5; ++g) bgO[g] = *(const bf16x8*)(bPtr[g] + 32);
    SCHED();

    #pragma unroll
    for (int it = 0; it < 16; ++it) {
        const int cur = it & 1;
        if (it < 15) { asm volatile("s_waitcnt vmcnt(7)" ::: "memory"); }
        else         { asm volatile("s_waitcnt vmcnt(0)" ::: "memory"); }
        SCHED(); SBAR(); SCHED();
        bf16x8 af[4];
        #pragma unroll
        for (int i = 0; i < 4; ++i)
            af[i] = *(const bf16x8*)&a_s[cur][(wr * 64 + i * 16 + fr) * 32 + l4 * 8];
        #pragma unroll
        for (int i = 0; i < 4; ++i)
            #pragma unroll
            for (int g = 0; g < 5; ++g)
                acc[i][g] = __builtin_amdgcn_mfma_f32_16x16x32_bf16(
                    cur ? bgO[g] : bgE[g], af[i], acc[i][g], 0, 0, 0);
        SCHED();
        if (it + 2 < 16) {
            #pragma unroll
            for (int g = 0; g < 5; ++g) {
                if (cur) bgO[g] = *(const bf16x8*)(bPtr[g] + (it + 2) * 32);
                else     bgE[g] = *(const bf16x8*)(bPtr[g] + (it + 2) * 32);
            }
        }
        SCHED(); SBAR(); SCHED();
        if (it + 2 < 16) {
            #pragma unroll
            for (int q = 0; q < 2; ++q)
                GLD16(aSrc[q] + (it + 2) * 32, &a_s[cur][(wave * 2 + q) * 512]);
        }
        SCHED();
    }

    // Epilogue: lane owns row r, 4 consecutive j.
    const int j0 = c0 + wc * 16 + l4 * 4;
    const float4 bfl4 = *(const float4*)(U_f_b + j0);
    const float4 bfr4 = *(const float4*)(U_f_b + 256 + j0);
    const float4 bi4  = *(const float4*)(b_iou + j0);
    const float4 bo4  = *(const float4*)(b_iou + 256 + j0);
    const float4 bu4  = *(const float4*)(b_iou + 512 + j0);
    #pragma unroll
    for (int i = 0; i < 4; ++i) {
        const int r  = bm0 + wr * 64 + i * 16 + fr;
        const int rc = r < M ? r : M - 1;
        const int tl   = rc >> lvl;
        const int idx  = rc & ((1 << lvl) - 1);
        const int cls  = tl * (2 << lvl) + 2 * idx;
        const int node = (tree0 + tl) * NPT + (1 << lvl) - 1 + idx;
        const us8 cml = *(const us8*)(cm_c + (long)cls * 512 + j0 * 2);
        const us8 cmr = *(const us8*)(cm_c + (long)(cls + 1) * 512 + j0 * 2);
        us4 sh, ss; us8 scm;
        #pragma unroll
        for (int q = 0; q < 4; ++q) {
            const float flv = fsigm(acc[i][0][q] + ((const float*)&bfl4)[q]);
            const float frv = fsigm(acc[i][1][q] + ((const float*)&bfr4)[q]);
            const float iv  = fsigm(acc[i][2][q] + ((const float*)&bi4)[q]);
            const float ov  = fsigm(acc[i][3][q] + ((const float*)&bo4)[q]);
            const float uv  = ftanh(acc[i][4][q] + ((const float*)&bu4)[q]);
            const float ccl = bits2f(cml[2 * q]), mhl = bits2f(cml[2 * q + 1]);
            const float ccr = bits2f(cmr[2 * q]), mhr = bits2f(cmr[2 * q + 1]);
            const float cv  = iv * uv + flv * ccl + frv * ccr;
            const float hv  = ov * ftanh(cv);
            const float mhv = fmaxf(hv, fmaxf(mhl, mhr));
            sh[q] = f2bits(hv); ss[q] = f2bits(hv + mhv);
            scm[2 * q] = f2bits(cv); scm[2 * q + 1] = f2bits(mhv);
        }
        if (r < M) {
            *(us4*)(h_p + (long)r * HS + j0)       = sh;
            *(us8*)(cm_p + (long)r * 512 + j0 * 2) = scm;
            *(us4*)(s_full + (long)node * HS + j0) = ss;
        }
    }
}

// ---------------------------------------------------------------------------
// Final logits: out[node,0:4] = s_full[node]@lin_w + lin_b. Wave per node.
// ---------------------------------------------------------------------------
__global__ __launch_bounds__(256) void logits_k(
    const bf16* __restrict__ s_full, const float* __restrict__ lin_w,
    const float* __restrict__ lin_b, float* __restrict__ out)
{
    const int wave = threadIdx.x >> 6, lane = threadIdx.x & 63;
    const int node = blockIdx.x * 4 + wave;
    const int j0   = lane * 4;
    const us4 v = *(const us4*)(s_full + (long)node * HS + j0);
    float p0 = 0.f, p1 = 0.f, p2 = 0.f, p3 = 0.f;
    #pragma unroll
    for (int q = 0; q < 4; ++q) {
        const float s  = bits2f(v[q]);
        const float4 w = *(const float4*)(lin_w + (j0 + q) * 4);
        p0 += s * w.x; p1 += s * w.y; p2 += s * w.z; p3 += s * w.w;
    }
    #pragma unroll
    for (int m = 1; m < 64; m <<= 1) {
        p0 += __shfl_xor(p0, m); p1 += __shfl_xor(p1, m);
        p2 += __shfl_xor(p2, m); p3 += __shfl_xor(p3, m);
    }
    if (lane == 0) {
        float4 r;
        r.x = p0 + lin_b[0]; r.y = p1 + lin_b[1];
        r.z = p2 + lin_b[2]; r.w = p3 + lin_b[3];
        *(float4*)(out + (long)node * 4) = r;
    }
}

// ---------------------------------------------------------------------------
extern "C" void kernel_launch(void* const* d_in, const int* in_sizes, int n_in,
                              void* d_out, int out_size, void* d_ws, size_t ws_size,
                              hipStream_t stream) {
    const int*   wordid = (const int*)d_in[0];
    const int*   mask   = (const int*)d_in[1];
    const float* emb    = (const float*)d_in[2];
    const float* W_iou  = (const float*)d_in[3];
    const float* U_iou  = (const float*)d_in[4];
    const float* U_f_w  = (const float*)d_in[5];
    const float* U_f_b  = (const float*)d_in[6];
    const float* b_iou  = (const float*)d_in[7];
    const float* lin_w  = (const float*)d_in[8];
    const float* lin_b  = (const float*)d_in[9];
    float* out = (float*)d_out;

    const size_t wElems = (size_t)WT_ELEMS + UT_ELEMS;    // 851,968
    const size_t sElems = (size_t)NNODES * HS;            // 33,521,664
    const size_t xElems = (size_t)NL * HS;                // 16,777,216
    auto need = [&](int T) -> size_t {
        return (wElems + sElems + xElems + (size_t)T * 589824) * 2;
    };
    int T = 8;
    const int cands[4] = {128, 64, 32, 16};
    for (int ci = 0; ci < 4; ++ci) {
        if (need(cands[ci]) <= ws_size) { T = cands[ci]; break; }
    }

    bf16* Wt     = (bf16*)d_ws;
    bf16* Ut     = Wt + WT_ELEMS;
    bf16* s_full = Ut + UT_ELEMS;
    bf16* x_bf   = s_full + sElems;
    bf16* hA  = x_bf + xElems;
    bf16* cmA = hA  + (size_t)T * 512 * HS;
    bf16* hB  = cmA + (size_t)T * 512 * HS * 2;
    bf16* cmB = hB  + (size_t)T * 256 * HS;

    prep_w<<<(int)((wElems + 255) / 256), 256, 0, stream>>>(
        W_iou, U_f_w, U_iou, Wt, Ut);
    gather_x<<<NL / 4, 256, 0, stream>>>(wordid, mask, emb, x_bf);

    for (int tree0 = 0; tree0 < NTREES; tree0 += T) {
        leaf_fused<<<dim3(T * 512 / 128, 8), 256, 0, stream>>>(
            x_bf, Wt, b_iou, hA, cmA, s_full, tree0);
        bool childIsA = true;
        for (int l = 8; l >= 0; --l) {
            bf16 *hc, *cmc, *hp, *cmp;
            if (childIsA) { hc = hA; cmc = cmA; hp = hB; cmp = cmB; }
            else          { hc = hB; cmc = cmB; hp = hA; cmp = cmA; }
            const int M = T << l;
            level_fused<<<dim3((M + 127) / 128, 8), 256, 0, stream>>>(
                hc, cmc, Ut, U_f_b, b_iou, hp, cmp, s_full, l, M, tree0);
            childIsA = !childIsA;
        }
    }
    logits_k<<<NNODES / 4, 256, 0, stream>>>(s_full, lin_w, lin_b, out);
}

// Round 10
// 422.815 us; speedup vs baseline: 1.2309x; 1.2309x over previous
//
#include <hip/hip_runtime.h>
#include <hip/hip_bf16.h>

// TreeLSTM, 128 perfect binary trees, depth 9, H=256. N=130944 nodes.
//
// R9 = revert-to-best-known: R6's 2-phase single-__syncthreads K-loop
// (compiler-managed waitcnts; GLD16 A+B into LDS double-buffer) combined
// with R7's gather_x pre-pass (leaf A = pure GLD16 from x_bf). Swapped
// MFMA operands (j in reg dim) + vectorized epilogues. prep_w and gather_x
// merged into one dispatch.
//
// ws (bf16): Wt[768*256], Ut[1280*512], s_full[N*256], x_bf[65536*256],
//            hA,cmA [T*512 rows], hB,cmB [T*256 rows]  (T=128: 253 MiB)

#define NTREES 128
#define NPT    1023
#define HS     256
#define NNODES (NTREES * NPT)
#define NL     (NTREES * 512)

typedef __hip_bfloat16 bf16;
typedef unsigned short us8 __attribute__((ext_vector_type(8)));
typedef unsigned short us4 __attribute__((ext_vector_type(4)));
typedef short bf16x8 __attribute__((ext_vector_type(8)));
typedef float f32x4 __attribute__((ext_vector_type(4)));

typedef __attribute__((address_space(1))) const void gvoid;
typedef __attribute__((address_space(3))) void svoid;
#define GLD16(gp, lp) \
    __builtin_amdgcn_global_load_lds((gvoid*)(gp), (svoid*)(lp), 16, 0, 0)

__device__ __forceinline__ float bits2f(unsigned short b) {
    return __uint_as_float(((unsigned)b) << 16);
}
__device__ __forceinline__ unsigned short f2bits(float x) {
    bf16 h = __float2bfloat16(x);
    return *reinterpret_cast<unsigned short*>(&h);
}
__device__ __forceinline__ float fsigm(float x) {
    return __builtin_amdgcn_rcpf(1.0f + __expf(-x));
}
__device__ __forceinline__ float ftanh(float x) {
    return 1.0f - 2.0f * __builtin_amdgcn_rcpf(1.0f + __expf(2.0f * x));
}

// ---------------------------------------------------------------------------
// prep+gather merged: blocks [0, PREPB) transpose weights to bf16;
// blocks [PREPB, PREPB+NL/4) gather x_bf = mask ? bf16(emb[wordid]) : 0.
// ---------------------------------------------------------------------------
#define WT_ELEMS (768 * 256)
#define UT_ELEMS (1280 * 512)
#define PW_ELEMS (WT_ELEMS + UT_ELEMS)            // 851,968
#define PREPB    ((PW_ELEMS + 255) / 256)         // 3329

__global__ __launch_bounds__(256) void prep_all(
    const float* __restrict__ W_iou, const float* __restrict__ U_f_w,
    const float* __restrict__ U_iou,
    const int* __restrict__ wordid, const int* __restrict__ mask,
    const float* __restrict__ emb,
    bf16* __restrict__ Wt, bf16* __restrict__ Ut, bf16* __restrict__ x_bf)
{
    if (blockIdx.x < PREPB) {
        const int i = blockIdx.x * 256 + threadIdx.x;
        if (i < WT_ELEMS) {
            const int n = i >> 8, k = i & 255;
            Wt[i] = __float2bfloat16(W_iou[k * 768 + n]);
        } else if (i < PW_ELEMS) {
            const int j = i - WT_ELEMS;
            const int n = j >> 9, k = j & 511;
            const float v = (n < 512) ? U_f_w[k * 512 + n]
                                      : U_iou[k * 768 + (n - 512)];
            Ut[j] = __float2bfloat16(v);
        }
        return;
    }
    const int wave = threadIdx.x >> 6, lane = threadIdx.x & 63;
    const int gr   = (blockIdx.x - PREPB) * 4 + wave;
    const int node = (gr >> 9) * NPT + 511 + (gr & 511);
    const int j0   = lane * 4;
    us4 v;
    if (mask[node]) {
        const float4 f = *(const float4*)(emb + (long)wordid[node] * HS + j0);
        v[0] = f2bits(f.x); v[1] = f2bits(f.y);
        v[2] = f2bits(f.z); v[3] = f2bits(f.w);
    } else {
        v[0] = v[1] = v[2] = v[3] = 0;
    }
    *(us4*)(x_bf + (long)gr * HS + j0) = v;
}

// ---------------------------------------------------------------------------
// Fused leaf. Tile 128 rows x (32j x 3 gates). 2-phase __syncthreads loop.
// A: 8 GLD16 (2/wave) from x_bf; B: 6 GLD16 (waves 0-2, 2 each) from Wt.
// ---------------------------------------------------------------------------
__global__ __launch_bounds__(256) void leaf_fused(
    const bf16* __restrict__ x_bf, const bf16* __restrict__ Wt,
    const float* __restrict__ b_iou,
    bf16* __restrict__ h_s, bf16* __restrict__ cm_s,
    bf16* __restrict__ s_full, const int tree0)
{
    __shared__ __align__(16) short a_s[2][128 * 32];
    __shared__ __align__(16) short b_s[2][96 * 32];
    const int t    = threadIdx.x;
    const int bm0  = blockIdx.x * 128;
    const int c0   = blockIdx.y * 32;
    const int lane = t & 63, wave = t >> 6;
    const int l4a = lane >> 2, k8 = (lane & 3) * 8;

    const bf16* aSrc[2];
    #pragma unroll
    for (int q = 0; q < 2; ++q) {
        const int row = (wave * 2 + q) * 16 + l4a;
        aSrc[q] = x_bf + (long)(tree0 * 512 + bm0 + row) * HS + k8;
    }
    const int bCnt = (wave < 3) ? 2 : 0;
    const int bStart = wave * 2;
    const bf16* bSrc[2];
    #pragma unroll
    for (int q = 0; q < 2; ++q) {
        int rb = (bStart + q) * 16 + l4a;
        if (rb > 95) rb = 95;
        const int g = rb >> 5, jl = rb & 31;
        bSrc[q] = Wt + (long)(g * 256 + c0 + jl) * 256 + k8;
    }

    const int wr = wave >> 1, wc = wave & 1;
    const int fr = lane & 15, l4 = lane >> 4;

    f32x4 acc[4][3];
    #pragma unroll
    for (int i = 0; i < 4; ++i)
        #pragma unroll
        for (int g = 0; g < 3; ++g) acc[i][g] = (f32x4){0.f, 0.f, 0.f, 0.f};

    auto stage = [&](int buf, int kt) {
        #pragma unroll
        for (int q = 0; q < 2; ++q)
            GLD16(aSrc[q] + kt, &a_s[buf][(wave * 2 + q) * 512]);
        #pragma unroll
        for (int q = 0; q < 2; ++q)
            if (q < bCnt) GLD16(bSrc[q] + kt, &b_s[buf][(bStart + q) * 512]);
    };

    stage(0, 0);
    __syncthreads();
    int cur = 0;
    for (int kt = 0; kt < 256; kt += 32) {
        const int nk = kt + 32;
        if (nk < 256) stage(cur ^ 1, nk);
        bf16x8 af[4], bg[3];
        #pragma unroll
        for (int i = 0; i < 4; ++i)
            af[i] = *(const bf16x8*)&a_s[cur][(wr * 64 + i * 16 + fr) * 32 + l4 * 8];
        #pragma unroll
        for (int g = 0; g < 3; ++g)
            bg[g] = *(const bf16x8*)&b_s[cur][(g * 32 + wc * 16 + fr) * 32 + l4 * 8];
        #pragma unroll
        for (int i = 0; i < 4; ++i)
            #pragma unroll
            for (int g = 0; g < 3; ++g)
                acc[i][g] = __builtin_amdgcn_mfma_f32_16x16x32_bf16(
                    bg[g], af[i], acc[i][g], 0, 0, 0);   // swapped: j in reg dim
        __syncthreads();
        cur ^= 1;
    }

    // Epilogue: lane owns row r (fr), 4 consecutive j (reg q).
    const int j0 = c0 + wc * 16 + l4 * 4;
    const float4 bi4 = *(const float4*)(b_iou + j0);
    const float4 bo4 = *(const float4*)(b_iou + 256 + j0);
    const float4 bu4 = *(const float4*)(b_iou + 512 + j0);
    #pragma unroll
    for (int i = 0; i < 4; ++i) {
        const int r    = bm0 + wr * 64 + i * 16 + fr;
        const int gr   = tree0 * 512 + r;
        const int node = (gr >> 9) * NPT + 511 + (gr & 511);
        us4 sh, ss; us8 scm;
        #pragma unroll
        for (int q = 0; q < 4; ++q) {
            const float iv = fsigm(acc[i][0][q] + ((const float*)&bi4)[q]);
            const float ov = fsigm(acc[i][1][q] + ((const float*)&bo4)[q]);
            const float uv = ftanh(acc[i][2][q] + ((const float*)&bu4)[q]);
            const float cv  = iv * uv;
            const float hv  = ov * ftanh(cv);
            const float mhv = fmaxf(hv, 0.0f);
            sh[q] = f2bits(hv); ss[q] = f2bits(hv + mhv);
            scm[2 * q] = f2bits(cv); scm[2 * q + 1] = f2bits(mhv);
        }
        *(us4*)(h_s + (long)r * HS + j0)        = sh;
        *(us8*)(cm_s + (long)r * 512 + j0 * 2)  = scm;
        *(us4*)(s_full + (long)node * HS + j0)  = ss;
    }
}

// ---------------------------------------------------------------------------
// Fused level. Tile 128 rows x (32j x 5 gates). 2-phase __syncthreads loop.
// A: 8 GLD16 (2/wave); B: 10 GLD16 (waves {3,3,2,2}) from Ut.
// ---------------------------------------------------------------------------
__global__ __launch_bounds__(256) void level_fused(
    const bf16* __restrict__ h_child, const bf16* __restrict__ cm_c,
    const bf16* __restrict__ Ut,
    const float* __restrict__ U_f_b, const float* __restrict__ b_iou,
    bf16* __restrict__ h_p, bf16* __restrict__ cm_p,
    bf16* __restrict__ s_full, const int lvl, const int M, const int tree0)
{
    __shared__ __align__(16) short a_s[2][128 * 32];
    __shared__ __align__(16) short b_s[2][160 * 32];
    const int t    = threadIdx.x;
    const int bm0  = blockIdx.x * 128;
    const int c0   = blockIdx.y * 32;
    const int lane = t & 63, wave = t >> 6;
    const int l4a = lane >> 2, k8 = (lane & 3) * 8;

    const bf16* aSrc[2];
    #pragma unroll
    for (int q = 0; q < 2; ++q) {
        int p = bm0 + (wave * 2 + q) * 16 + l4a;
        if (p >= M) p = M - 1;
        const int tl  = p >> lvl;
        const int idx = p & ((1 << lvl) - 1);
        const int cls = tl * (2 << lvl) + 2 * idx;
        aSrc[q] = h_child + (long)cls * HS + k8;  // 512 contiguous (2 children)
    }
    const int bCnt   = (wave < 2) ? 3 : 2;
    const int bStart = (wave < 2) ? wave * 3 : 6 + (wave - 2) * 2;
    const bf16* bSrc[3];
    #pragma unroll
    for (int q = 0; q < 3; ++q) {
        int rb = (bStart + q) * 16 + l4a;
        if (rb > 159) rb = 159;
        const int g = rb >> 5, jl = rb & 31;
        bSrc[q] = Ut + (long)(g * 256 + c0 + jl) * 512 + k8;
    }

    const int wr = wave >> 1, wc = wave & 1;
    const int fr = lane & 15, l4 = lane >> 4;

    f32x4 acc[4][5];
    #pragma unroll
    for (int i = 0; i < 4; ++i)
        #pragma unroll
        for (int g = 0; g < 5; ++g) acc[i][g] = (f32x4){0.f, 0.f, 0.f, 0.f};

    auto stage = [&](int buf, int kt) {
        #pragma unroll
        for (int q = 0; q < 2; ++q)
            GLD16(aSrc[q] + kt, &a_s[buf][(wave * 2 + q) * 512]);
        #pragma unroll
        for (int q = 0; q < 3; ++q)
            if (q < bCnt) GLD16(bSrc[q] + kt, &b_s[buf][(bStart + q) * 512]);
    };

    stage(0, 0);
    __syncthreads();
    int cur = 0;
    for (int kt = 0; kt < 512; kt += 32) {
        const int nk = kt + 32;
        if (nk < 512) stage(cur ^ 1, nk);
        bf16x8 af[4], bg[5];
        #pragma unroll
        for (int i = 0; i < 4; ++i)
            af[i] = *(const bf16x8*)&a_s[cur][(wr * 64 + i * 16 + fr) * 32 + l4 * 8];
        #pragma unroll
        for (int g = 0; g < 5; ++g)
            bg[g] = *(const bf16x8*)&b_s[cur][(g * 32 + wc * 16 + fr) * 32 + l4 * 8];
        #pragma unroll
        for (int i = 0; i < 4; ++i)
            #pragma unroll
            for (int g = 0; g < 5; ++g)
                acc[i][g] = __builtin_amdgcn_mfma_f32_16x16x32_bf16(
                    bg[g], af[i], acc[i][g], 0, 0, 0);   // swapped: j in reg dim
        __syncthreads();
        cur ^= 1;
    }

    // Epilogue: lane owns row r, 4 consecutive j.
    const int j0 = c0 + wc * 16 + l4 * 4;
    const float4 bfl4 = *(const float4*)(U_f_b + j0);
    const float4 bfr4 = *(const float4*)(U_f_b + 256 + j0);
    const float4 bi4  = *(const float4*)(b_iou + j0);
    const float4 bo4  = *(const float4*)(b_iou + 256 + j0);
    const float4 bu4  = *(const float4*)(b_iou + 512 + j0);
    #pragma unroll
    for (int i = 0; i < 4; ++i) {
        const int r  = bm0 + wr * 64 + i * 16 + fr;
        const int rc = r < M ? r : M - 1;
        const int tl   = rc >> lvl;
        const int idx  = rc & ((1 << lvl) - 1);
        const int cls  = tl * (2 << lvl) + 2 * idx;
        const int node = (tree0 + tl) * NPT + (1 << lvl) - 1 + idx;
        const us8 cml = *(const us8*)(cm_c + (long)cls * 512 + j0 * 2);
        const us8 cmr = *(const us8*)(cm_c + (long)(cls + 1) * 512 + j0 * 2);
        us4 sh, ss; us8 scm;
        #pragma unroll
        for (int q = 0; q < 4; ++q) {
            const float flv = fsigm(acc[i][0][q] + ((const float*)&bfl4)[q]);
            const float frv = fsigm(acc[i][1][q] + ((const float*)&bfr4)[q]);
            const float iv  = fsigm(acc[i][2][q] + ((const float*)&bi4)[q]);
            const float ov  = fsigm(acc[i][3][q] + ((const float*)&bo4)[q]);
            const float uv  = ftanh(acc[i][4][q] + ((const float*)&bu4)[q]);
            const float ccl = bits2f(cml[2 * q]), mhl = bits2f(cml[2 * q + 1]);
            const float ccr = bits2f(cmr[2 * q]), mhr = bits2f(cmr[2 * q + 1]);
            const float cv  = iv * uv + flv * ccl + frv * ccr;
            const float hv  = ov * ftanh(cv);
            const float mhv = fmaxf(hv, fmaxf(mhl, mhr));
            sh[q] = f2bits(hv); ss[q] = f2bits(hv + mhv);
            scm[2 * q] = f2bits(cv); scm[2 * q + 1] = f2bits(mhv);
        }
        if (r < M) {
            *(us4*)(h_p + (long)r * HS + j0)       = sh;
            *(us8*)(cm_p + (long)r * 512 + j0 * 2) = scm;
            *(us4*)(s_full + (long)node * HS + j0) = ss;
        }
    }
}

// ---------------------------------------------------------------------------
// Final logits: out[node,0:4] = s_full[node]@lin_w + lin_b. Wave per node.
// ---------------------------------------------------------------------------
__global__ __launch_bounds__(256) void logits_k(
    const bf16* __restrict__ s_full, const float* __restrict__ lin_w,
    const float* __restrict__ lin_b, float* __restrict__ out)
{
    const int wave = threadIdx.x >> 6, lane = threadIdx.x & 63;
    const int node = blockIdx.x * 4 + wave;
    const int j0   = lane * 4;
    const us4 v = *(const us4*)(s_full + (long)node * HS + j0);
    float p0 = 0.f, p1 = 0.f, p2 = 0.f, p3 = 0.f;
    #pragma unroll
    for (int q = 0; q < 4; ++q) {
        const float s  = bits2f(v[q]);
        const float4 w = *(const float4*)(lin_w + (j0 + q) * 4);
        p0 += s * w.x; p1 += s * w.y; p2 += s * w.z; p3 += s * w.w;
    }
    #pragma unroll
    for (int m = 1; m < 64; m <<= 1) {
        p0 += __shfl_xor(p0, m); p1 += __shfl_xor(p1, m);
        p2 += __shfl_xor(p2, m); p3 += __shfl_xor(p3, m);
    }
    if (lane == 0) {
        float4 r;
        r.x = p0 + lin_b[0]; r.y = p1 + lin_b[1];
        r.z = p2 + lin_b[2]; r.w = p3 + lin_b[3];
        *(float4*)(out + (long)node * 4) = r;
    }
}

// ---------------------------------------------------------------------------
extern "C" void kernel_launch(void* const* d_in, const int* in_sizes, int n_in,
                              void* d_out, int out_size, void* d_ws, size_t ws_size,
                              hipStream_t stream) {
    const int*   wordid = (const int*)d_in[0];
    const int*   mask   = (const int*)d_in[1];
    const float* emb    = (const float*)d_in[2];
    const float* W_iou  = (const float*)d_in[3];
    const float* U_iou  = (const float*)d_in[4];
    const float* U_f_w  = (const float*)d_in[5];
    const float* U_f_b  = (const float*)d_in[6];
    const float* b_iou  = (const float*)d_in[7];
    const float* lin_w  = (const float*)d_in[8];
    const float* lin_b  = (const float*)d_in[9];
    float* out = (float*)d_out;

    const size_t wElems = (size_t)PW_ELEMS;               // 851,968
    const size_t sElems = (size_t)NNODES * HS;            // 33,521,664
    const size_t xElems = (size_t)NL * HS;                // 16,777,216
    auto need = [&](int T) -> size_t {
        return (wElems + sElems + xElems + (size_t)T * 589824) * 2;
    };
    int T = 8;
    const int cands[4] = {128, 64, 32, 16};
    for (int ci = 0; ci < 4; ++ci) {
        if (need(cands[ci]) <= ws_size) { T = cands[ci]; break; }
    }

    bf16* Wt     = (bf16*)d_ws;
    bf16* Ut     = Wt + WT_ELEMS;
    bf16* s_full = Ut + UT_ELEMS;
    bf16* x_bf   = s_full + sElems;
    bf16* hA  = x_bf + xElems;
    bf16* cmA = hA  + (size_t)T * 512 * HS;
    bf16* hB  = cmA + (size_t)T * 512 * HS * 2;
    bf16* cmB = hB  + (size_t)T * 256 * HS;

    prep_all<<<PREPB + NL / 4, 256, 0, stream>>>(
        W_iou, U_f_w, U_iou, wordid, mask, emb, Wt, Ut, x_bf);

    for (int tree0 = 0; tree0 < NTREES; tree0 += T) {
        leaf_fused<<<dim3(T * 512 / 128, 8), 256, 0, stream>>>(
            x_bf, Wt, b_iou, hA, cmA, s_full, tree0);
        bool childIsA = true;
        for (int l = 8; l >= 0; --l) {
            bf16 *hc, *cmc, *hp, *cmp;
            if (childIsA) { hc = hA; cmc = cmA; hp = hB; cmp = cmB; }
            else          { hc = hB; cmc = cmB; hp = hA; cmp = cmA; }
            const int M = T << l;
            level_fused<<<dim3((M + 127) / 128, 8), 256, 0, stream>>>(
                hc, cmc, Ut, U_f_b, b_iou, hp, cmp, s_full, l, M, tree0);
            childIsA = !childIsA;
        }
    }
    logits_k<<<NNODES / 4, 256, 0, stream>>>(s_full, lin_w, lin_b, out);
}